// Round 1
// baseline (498.672 us; speedup 1.0000x reference)
//
#include <hip/hip_runtime.h>
#include <math.h>

#define NEG_V (-1e30f)
#define SLOPE_V 0.01f
#define EPS_V 1e-5f

// ---------------------------------------------------------------------------
// Kernel A: C[M,N] = A[M,K] @ W[K,N] + bias[N]   (M=1024, N=768, K=768)
// 64x64 tile, BK=16, 256 threads, 4x4 microtile.
// ---------------------------------------------------------------------------
__global__ __launch_bounds__(256) void gemm_bias_k(
    const float* __restrict__ A, const float* __restrict__ W,
    const float* __restrict__ bias, float* __restrict__ C,
    int M, int N, int K)
{
    const int BM = 64, BN = 64, BK = 16;
    __shared__ float As[BK][BM + 1];
    __shared__ float Ws[BK][BN + 1];
    int row0 = blockIdx.y * BM;
    int col0 = blockIdx.x * BN;
    int tid = threadIdx.x;
    int tx = tid & 15, ty = tid >> 4;
    float acc[4][4] = {};
    for (int k0 = 0; k0 < K; k0 += BK) {
#pragma unroll
        for (int i = 0; i < 4; i++) {
            int m = (tid >> 4) + i * 16;
            int k = tid & 15;
            As[k][m] = A[(size_t)(row0 + m) * K + k0 + k];
        }
#pragma unroll
        for (int i = 0; i < 4; i++) {
            int k = (tid >> 6) + i * 4;
            int n = tid & 63;
            Ws[k][n] = W[(size_t)(k0 + k) * N + col0 + n];
        }
        __syncthreads();
#pragma unroll
        for (int k = 0; k < BK; k++) {
            float a[4], w[4];
#pragma unroll
            for (int i = 0; i < 4; i++) a[i] = As[k][ty * 4 + i];
#pragma unroll
            for (int j = 0; j < 4; j++) w[j] = Ws[k][tx * 4 + j];
#pragma unroll
            for (int i = 0; i < 4; i++)
#pragma unroll
                for (int j = 0; j < 4; j++)
                    acc[i][j] = fmaf(a[i], w[j], acc[i][j]);
        }
        __syncthreads();
    }
#pragma unroll
    for (int i = 0; i < 4; i++) {
        int m = row0 + ty * 4 + i;
#pragma unroll
        for (int j = 0; j < 4; j++) {
            int n = col0 + tx * 4 + j;
            C[(size_t)m * N + n] = acc[i][j] + bias[n];
        }
    }
}

// ---------------------------------------------------------------------------
// Kernel B: s[m, 0:64] = h[m,:] @ A1[0:768, :]      (s_src)
//           s[m,64:128] = h[m,:] @ A1[768:1536, :]  (s_tgt)
// M=1024, K=768. BM=32, BN=128 (full), BK=32, 256 threads, 2x8 microtile.
// ---------------------------------------------------------------------------
__global__ __launch_bounds__(256) void sproj_k(
    const float* __restrict__ h, const float* __restrict__ A1,
    float* __restrict__ s, int K)
{
    const int BM = 32, BK = 32;
    __shared__ float Hs[BK][BM + 1];
    __shared__ float Ws[BK][129];
    int row0 = blockIdx.x * BM;
    int tid = threadIdx.x;
    int tx = tid & 15, ty = tid >> 4;
    float acc[2][8] = {};
    for (int k0 = 0; k0 < K; k0 += BK) {
#pragma unroll
        for (int i = 0; i < 4; i++) {
            int k = tid & 31;
            int m = (tid >> 5) + i * 8;
            Hs[k][m] = h[(size_t)(row0 + m) * K + k0 + k];
        }
#pragma unroll
        for (int i = 0; i < 16; i++) {
            int col = tid & 127;
            int kr = (tid >> 7) + i * 2;
            int r = (col < 64) ? (k0 + kr) : (768 + k0 + kr);
            int c = col & 63;
            Ws[kr][col] = A1[(size_t)r * 64 + c];
        }
        __syncthreads();
#pragma unroll
        for (int k = 0; k < BK; k++) {
            float a0 = Hs[k][ty * 2 + 0];
            float a1 = Hs[k][ty * 2 + 1];
#pragma unroll
            for (int j = 0; j < 8; j++) {
                float w = Ws[k][tx * 8 + j];
                acc[0][j] = fmaf(a0, w, acc[0][j]);
                acc[1][j] = fmaf(a1, w, acc[1][j]);
            }
        }
        __syncthreads();
    }
#pragma unroll
    for (int i = 0; i < 2; i++) {
        int m = row0 + ty * 2 + i;
#pragma unroll
        for (int j = 0; j < 8; j++) {
            s[(size_t)m * 128 + tx * 8 + j] = acc[i][j];
        }
    }
}

// ---------------------------------------------------------------------------
// Kernel C: masked logits.
// e[b,i,j] = sum_h relu(s_src[b,i,h] + s_tgt[b,j,h] + ab1[h]) * A2[h] + ab2
// leaky-relu, mask -> p buffer. grid (i_tile=8, b=8), block 256.
// ---------------------------------------------------------------------------
__global__ __launch_bounds__(256) void score_k(
    const float* __restrict__ s, const int* __restrict__ adj,
    const float* __restrict__ ab1, const float* __restrict__ A2,
    const float* __restrict__ ab2, float* __restrict__ p)
{
    __shared__ float st[128][65];
    __shared__ float ss[16][65];
    __shared__ float a2s[64], ab1s[64];
    int b = blockIdx.y;
    int i0 = blockIdx.x * 16;
    int tid = threadIdx.x;
    for (int idx = tid; idx < 128 * 64; idx += 256) {
        int j = idx >> 6, hh = idx & 63;
        st[j][hh] = s[(size_t)(b * 128 + j) * 128 + 64 + hh];
    }
    for (int idx = tid; idx < 16 * 64; idx += 256) {
        int i = idx >> 6, hh = idx & 63;
        ss[i][hh] = s[(size_t)(b * 128 + i0 + i) * 128 + hh];
    }
    if (tid < 64) { a2s[tid] = A2[tid]; ab1s[tid] = ab1[tid]; }
    __syncthreads();
    float ab2v = ab2[0];
    for (int pidx = tid; pidx < 16 * 128; pidx += 256) {
        int il = pidx >> 7, j = pidx & 127;
        float acc = 0.f;
#pragma unroll
        for (int hh = 0; hh < 64; hh++) {
            float v = ss[il][hh] + st[j][hh] + ab1s[hh];
            acc = fmaf(fmaxf(v, 0.f), a2s[hh], acc);
        }
        float e = acc + ab2v;
        e = (e > 0.f) ? e : SLOPE_V * e;
        size_t off = (size_t)b * 16384 + (size_t)(i0 + il) * 128 + j;
        int a = adj[off];
        p[off] = a ? e : NEG_V;
    }
}

// ---------------------------------------------------------------------------
// Kernel D: per-batch flattened softmax (max + exp in place + sum).
// Normalization (1/sum) is applied in the following GEMM's epilogue.
// grid 8 (one block per batch), block 256.
// ---------------------------------------------------------------------------
__global__ __launch_bounds__(256) void softmax_k(
    float* __restrict__ p, float* __restrict__ stats)
{
    int b = blockIdx.x;
    float* pb = p + (size_t)b * 16384;
    int tid = threadIdx.x;
    __shared__ float red[256];
    float mx = -3.4e38f;
    for (int i = tid; i < 16384; i += 256) mx = fmaxf(mx, pb[i]);
    red[tid] = mx;
    __syncthreads();
    for (int sft = 128; sft > 0; sft >>= 1) {
        if (tid < sft) red[tid] = fmaxf(red[tid], red[tid + sft]);
        __syncthreads();
    }
    mx = red[0];
    __syncthreads();
    float sum = 0.f;
    for (int i = tid; i < 16384; i += 256) {
        float v = expf(pb[i] - mx);
        pb[i] = v;
        sum += v;
    }
    red[tid] = sum;
    __syncthreads();
    for (int sft = 128; sft > 0; sft >>= 1) {
        if (tid < sft) red[tid] += red[tid + sft];
        __syncthreads();
    }
    if (tid == 0) stats[b] = red[0];
}

// ---------------------------------------------------------------------------
// Kernel E: batched feature_new[b] = (1/sum_b) * P[b](128x128) @ h[b](128x768)
// grid (ntile=12, mtile=2, b=8), block 256, 64x64 tile, 4x4 microtile.
// ---------------------------------------------------------------------------
__global__ __launch_bounds__(256) void attn_gemm_k(
    const float* __restrict__ p, const float* __restrict__ h,
    const float* __restrict__ stats, float* __restrict__ C)
{
    const int BM = 64, BN = 64, BK = 16;
    __shared__ float As[BK][BM + 1];
    __shared__ float Ws[BK][BN + 1];
    int b = blockIdx.z;
    const float* Ab = p + (size_t)b * 16384;
    const float* Bb = h + (size_t)b * 98304;
    float* Cb = C + (size_t)b * 98304;
    int row0 = blockIdx.y * BM;
    int col0 = blockIdx.x * BN;
    int tid = threadIdx.x;
    int tx = tid & 15, ty = tid >> 4;
    float acc[4][4] = {};
    for (int k0 = 0; k0 < 128; k0 += BK) {
#pragma unroll
        for (int i = 0; i < 4; i++) {
            int m = (tid >> 4) + i * 16;
            int k = tid & 15;
            As[k][m] = Ab[(size_t)(row0 + m) * 128 + k0 + k];
        }
#pragma unroll
        for (int i = 0; i < 4; i++) {
            int k = (tid >> 6) + i * 4;
            int n = tid & 63;
            Ws[k][n] = Bb[(size_t)(k0 + k) * 768 + col0 + n];
        }
        __syncthreads();
#pragma unroll
        for (int k = 0; k < BK; k++) {
            float a[4], w[4];
#pragma unroll
            for (int i = 0; i < 4; i++) a[i] = As[k][ty * 4 + i];
#pragma unroll
            for (int j = 0; j < 4; j++) w[j] = Ws[k][tx * 4 + j];
#pragma unroll
            for (int i = 0; i < 4; i++)
#pragma unroll
                for (int j = 0; j < 4; j++)
                    acc[i][j] = fmaf(a[i], w[j], acc[i][j]);
        }
        __syncthreads();
    }
    float alpha = 1.0f / stats[b];
#pragma unroll
    for (int i = 0; i < 4; i++) {
        int m = row0 + ty * 4 + i;
#pragma unroll
        for (int j = 0; j < 4; j++) {
            int n = col0 + tx * 4 + j;
            Cb[(size_t)m * 768 + n] = acc[i][j] * alpha;
        }
    }
}

// ---------------------------------------------------------------------------
// Kernel F1: g[b,d] = sum_i node[b,i,d].  grid (8, 3), block 256.
// ---------------------------------------------------------------------------
__global__ __launch_bounds__(256) void gsum_k(
    const float* __restrict__ node, float* __restrict__ g)
{
    int b = blockIdx.x;
    int d = blockIdx.y * 256 + threadIdx.x;
    float sum = 0.f;
    for (int i = 0; i < 128; i++)
        sum += node[(size_t)b * 98304 + (size_t)i * 768 + d];
    g[b * 768 + d] = sum;
}

// ---------------------------------------------------------------------------
// Kernel F2: batch-norm over axis 0 (8 graphs).  grid 3, block 256.
// ---------------------------------------------------------------------------
__global__ __launch_bounds__(256) void bnorm_k(
    const float* __restrict__ g, const float* __restrict__ gamma,
    const float* __restrict__ beta, float* __restrict__ out)
{
    int d = blockIdx.x * 256 + threadIdx.x;
    float v[8];
    float mean = 0.f;
#pragma unroll
    for (int b = 0; b < 8; b++) { v[b] = g[b * 768 + d]; mean += v[b]; }
    mean *= 0.125f;
    float var = 0.f;
#pragma unroll
    for (int b = 0; b < 8; b++) { float t = v[b] - mean; var += t * t; }
    var *= 0.125f;
    float inv = 1.0f / sqrtf(var + EPS_V);
#pragma unroll
    for (int b = 0; b < 8; b++)
        out[b * 768 + d] = gamma[d] * (v[b] - mean) * inv + beta[d];
}

// ---------------------------------------------------------------------------
extern "C" void kernel_launch(void* const* d_in, const int* in_sizes, int n_in,
                              void* d_out, int out_size, void* d_ws, size_t ws_size,
                              hipStream_t stream)
{
    const float* feature = (const float*)d_in[0];
    // d_in[1] = aspect: unused by the reference
    const int*   adj     = (const int*)d_in[2];
    const float* W0      = (const float*)d_in[3];
    const float* b0      = (const float*)d_in[4];
    const float* W1      = (const float*)d_in[5];
    const float* b1      = (const float*)d_in[6];
    const float* A1      = (const float*)d_in[7];
    const float* ab1     = (const float*)d_in[8];
    const float* A2      = (const float*)d_in[9];
    const float* ab2     = (const float*)d_in[10];
    const float* gamma   = (const float*)d_in[11];
    const float* beta    = (const float*)d_in[12];

    float* ws    = (float*)d_ws;
    float* h     = ws;                // 1024*768 = 786432
    float* s     = ws + 786432;       // 1024*128 = 131072
    float* p     = ws + 917504;       // 8*128*128 = 131072
    float* stats = ws + 1048576;      // 16
    float* g     = ws + 1048592;      // 8*768 = 6144

    float* out       = (float*)d_out;
    float* graph_out = out;           // (8,768)
    float* node_out  = out + 6144;    // (8,128,768); also layer-1 scratch

    const float* feat_in = feature;
    for (int layer = 0; layer < 2; layer++) {
        const float* W  = layer ? W1 : W0;
        const float* bb = layer ? b1 : b0;
        gemm_bias_k<<<dim3(12, 16), 256, 0, stream>>>(feat_in, W, bb, h, 1024, 768, 768);
        sproj_k<<<dim3(32), 256, 0, stream>>>(h, A1, s, 768);
        score_k<<<dim3(8, 8), 256, 0, stream>>>(s, adj, ab1, A2, ab2, p);
        softmax_k<<<dim3(8), 256, 0, stream>>>(p, stats);
        attn_gemm_k<<<dim3(12, 2, 8), 256, 0, stream>>>(p, h, stats, node_out);
        feat_in = node_out;
    }
    gsum_k<<<dim3(8, 3), 256, 0, stream>>>(node_out, g);
    bnorm_k<<<dim3(3), 256, 0, stream>>>(g, gamma, beta, graph_out);
}

// Round 2
// 287.808 us; speedup vs baseline: 1.7327x; 1.7327x over previous
//
#include <hip/hip_runtime.h>
#include <math.h>

#define NEG_V (-1e30f)
#define SLOPE_V 0.01f
#define EPS_V 1e-5f

// ---------------------------------------------------------------------------
// Shared fp32 GEMM mainloop: 64x64 output tile, BK=16, 256 threads, 4x4
// microtile. LDS rows padded to 68 floats (68*4=272 B = 16B-aligned rows ->
// float4 LDS reads stay aligned; inner b128 reads are 2-way-conflict max,
// which is free on gfx950).
//   A: row-major, lda elements/row, pre-offset to [row0][k_start]
//   B: row-major, ldb elements/row, pre-offset to [k_start][col0]
// ---------------------------------------------------------------------------
__device__ __forceinline__ void gemm_tile_loop(
    const float* __restrict__ A, int lda,
    const float* __restrict__ B, int ldb,
    int kLen, float (&acc)[4][4],
    float (*As)[68], float (*Ws)[68], int tid)
{
    const int tx = tid & 15, ty = tid >> 4;
    const int am = tid >> 2, akq = (tid & 3) * 4;        // A-stage: row, k-quad
    const int bk = tid >> 4, bcq = (tid & 15) * 4;       // B-stage: k, col-quad
    for (int k0 = 0; k0 < kLen; k0 += 16) {
        // stage A tile (64 rows x 16 k) via float4 along k, transpose to [k][m]
        float4 av = *(const float4*)(A + (size_t)am * lda + k0 + akq);
        As[akq + 0][am] = av.x;
        As[akq + 1][am] = av.y;
        As[akq + 2][am] = av.z;
        As[akq + 3][am] = av.w;
        // stage B tile (16 k x 64 cols) via float4 along cols, [k][n]
        *(float4*)&Ws[bk][bcq] = *(const float4*)(B + (size_t)(k0 + bk) * ldb + bcq);
        __syncthreads();
#pragma unroll
        for (int k = 0; k < 16; k++) {
            float4 a4 = *(const float4*)&As[k][ty * 4];
            float4 w4 = *(const float4*)&Ws[k][tx * 4];
            float a[4] = {a4.x, a4.y, a4.z, a4.w};
            float w[4] = {w4.x, w4.y, w4.z, w4.w};
#pragma unroll
            for (int i = 0; i < 4; i++)
#pragma unroll
                for (int j = 0; j < 4; j++)
                    acc[i][j] = fmaf(a[i], w[j], acc[i][j]);
        }
        __syncthreads();
    }
}

// ---------------------------------------------------------------------------
// Kernel A: C[M,N] = A[M,K] @ W[K,N] + bias[N]   (M=1024, N=768, K=768)
// grid (12, 16), block 256.
// ---------------------------------------------------------------------------
__global__ __launch_bounds__(256) void gemm_bias_k(
    const float* __restrict__ A, const float* __restrict__ W,
    const float* __restrict__ bias, float* __restrict__ C,
    int N, int K)
{
    __shared__ float As[16][68];
    __shared__ float Ws[16][68];
    int row0 = blockIdx.y * 64;
    int col0 = blockIdx.x * 64;
    int tid = threadIdx.x;
    int tx = tid & 15, ty = tid >> 4;
    float acc[4][4] = {};
    gemm_tile_loop(A + (size_t)row0 * K, K, W + col0, N, K, acc, As, Ws, tid);
#pragma unroll
    for (int i = 0; i < 4; i++) {
        int m = row0 + ty * 4 + i;
#pragma unroll
        for (int j = 0; j < 4; j++) {
            int n = col0 + tx * 4 + j;
            C[(size_t)m * N + n] = acc[i][j] + bias[n];
        }
    }
}

// ---------------------------------------------------------------------------
// Kernel B: split-K sproj. s[m, 0:64] = h[m,:] @ A1[0:768,:]
//                          s[m,64:128] = h[m,:] @ A1[768:1536,:]
// grid (nhalf=2, mtile=16, kchunk=4), block 256. s must be zeroed first;
// each chunk atomicAdds its 192-deep partial.
// ---------------------------------------------------------------------------
__global__ __launch_bounds__(256) void sproj_k(
    const float* __restrict__ h, const float* __restrict__ A1,
    float* __restrict__ s)
{
    __shared__ float As[16][68];
    __shared__ float Ws[16][68];
    int half = blockIdx.x;            // 0 = src, 1 = tgt
    int row0 = blockIdx.y * 64;
    int kc   = blockIdx.z;            // k chunk of 192
    int tid = threadIdx.x;
    int tx = tid & 15, ty = tid >> 4;
    float acc[4][4] = {};
    const float* Ablk = h + (size_t)row0 * 768 + kc * 192;
    const float* Bblk = A1 + (half ? (size_t)768 * 64 : 0) + (size_t)(kc * 192) * 64;
    gemm_tile_loop(Ablk, 768, Bblk, 64, 192, acc, As, Ws, tid);
#pragma unroll
    for (int i = 0; i < 4; i++) {
        int m = row0 + ty * 4 + i;
#pragma unroll
        for (int j = 0; j < 4; j++) {
            int n = half * 64 + tx * 4 + j;
            atomicAdd(&s[(size_t)m * 128 + n], acc[i][j]);
        }
    }
}

// ---------------------------------------------------------------------------
// Kernel C: masked logits.
// e[b,i,j] = sum_h relu(s_src[b,i,h] + s_tgt[b,j,h] + ab1[h]) * A2[h] + ab2
// grid (i_tile=8, b=8), block 256.
// ---------------------------------------------------------------------------
__global__ __launch_bounds__(256) void score_k(
    const float* __restrict__ s, const int* __restrict__ adj,
    const float* __restrict__ ab1, const float* __restrict__ A2,
    const float* __restrict__ ab2, float* __restrict__ p)
{
    __shared__ float st[128][65];
    __shared__ float ss[16][65];
    __shared__ float a2s[64], ab1s[64];
    int b = blockIdx.y;
    int i0 = blockIdx.x * 16;
    int tid = threadIdx.x;
    for (int idx = tid; idx < 128 * 64; idx += 256) {
        int j = idx >> 6, hh = idx & 63;
        st[j][hh] = s[(size_t)(b * 128 + j) * 128 + 64 + hh];
    }
    for (int idx = tid; idx < 16 * 64; idx += 256) {
        int i = idx >> 6, hh = idx & 63;
        ss[i][hh] = s[(size_t)(b * 128 + i0 + i) * 128 + hh];
    }
    if (tid < 64) { a2s[tid] = A2[tid]; ab1s[tid] = ab1[tid]; }
    __syncthreads();
    float ab2v = ab2[0];
    for (int pidx = tid; pidx < 16 * 128; pidx += 256) {
        int il = pidx >> 7, j = pidx & 127;
        float acc = 0.f;
#pragma unroll
        for (int hh = 0; hh < 64; hh++) {
            float v = ss[il][hh] + st[j][hh] + ab1s[hh];
            acc = fmaf(fmaxf(v, 0.f), a2s[hh], acc);
        }
        float e = acc + ab2v;
        e = (e > 0.f) ? e : SLOPE_V * e;
        size_t off = (size_t)b * 16384 + (size_t)(i0 + il) * 128 + j;
        int a = adj[off];
        p[off] = a ? e : NEG_V;
    }
}

// ---------------------------------------------------------------------------
// Kernel D: per-batch flattened softmax (max + exp in place + sum).
// 1/sum applied in the following GEMM epilogue. grid 8, block 1024.
// ---------------------------------------------------------------------------
__global__ __launch_bounds__(1024) void softmax_k(
    float* __restrict__ p, float* __restrict__ stats)
{
    int b = blockIdx.x;
    float* pb = p + (size_t)b * 16384;
    int tid = threadIdx.x;
    __shared__ float red[1024];
    float mx = -3.4e38f;
    for (int i = tid; i < 16384; i += 1024) mx = fmaxf(mx, pb[i]);
    red[tid] = mx;
    __syncthreads();
    for (int sft = 512; sft > 0; sft >>= 1) {
        if (tid < sft) red[tid] = fmaxf(red[tid], red[tid + sft]);
        __syncthreads();
    }
    mx = red[0];
    __syncthreads();
    float sum = 0.f;
    for (int i = tid; i < 16384; i += 1024) {
        float v = expf(pb[i] - mx);
        pb[i] = v;
        sum += v;
    }
    red[tid] = sum;
    __syncthreads();
    for (int sft = 512; sft > 0; sft >>= 1) {
        if (tid < sft) red[tid] += red[tid + sft];
        __syncthreads();
    }
    if (tid == 0) stats[b] = red[0];
}

// ---------------------------------------------------------------------------
// Kernel E: batched feature_new[b] = (1/sum_b) * P[b](128x128) @ h[b](128x768)
// grid (ntile=12, mtile=2, b=8), block 256.
// ---------------------------------------------------------------------------
__global__ __launch_bounds__(256) void attn_gemm_k(
    const float* __restrict__ p, const float* __restrict__ h,
    const float* __restrict__ stats, float* __restrict__ C)
{
    __shared__ float As[16][68];
    __shared__ float Ws[16][68];
    int b = blockIdx.z;
    int row0 = blockIdx.y * 64;
    int col0 = blockIdx.x * 64;
    int tid = threadIdx.x;
    int tx = tid & 15, ty = tid >> 4;
    float acc[4][4] = {};
    const float* Ablk = p + (size_t)b * 16384 + (size_t)row0 * 128;
    const float* Bblk = h + (size_t)b * 98304 + col0;
    gemm_tile_loop(Ablk, 128, Bblk, 768, 128, acc, As, Ws, tid);
    float alpha = 1.0f / stats[b];
    float* Cb = C + (size_t)b * 98304;
#pragma unroll
    for (int i = 0; i < 4; i++) {
        int m = row0 + ty * 4 + i;
#pragma unroll
        for (int j = 0; j < 4; j++) {
            int n = col0 + tx * 4 + j;
            Cb[(size_t)m * 768 + n] = acc[i][j] * alpha;
        }
    }
}

// ---------------------------------------------------------------------------
// Kernel F1: g[b,d] = sum_i node[b,i,d].  grid (8, 3), block 256.
// ---------------------------------------------------------------------------
__global__ __launch_bounds__(256) void gsum_k(
    const float* __restrict__ node, float* __restrict__ g)
{
    int b = blockIdx.x;
    int d = blockIdx.y * 256 + threadIdx.x;
    float sum = 0.f;
    for (int i = 0; i < 128; i++)
        sum += node[(size_t)b * 98304 + (size_t)i * 768 + d];
    g[b * 768 + d] = sum;
}

// ---------------------------------------------------------------------------
// Kernel F2: batch-norm over axis 0 (8 graphs).  grid 3, block 256.
// ---------------------------------------------------------------------------
__global__ __launch_bounds__(256) void bnorm_k(
    const float* __restrict__ g, const float* __restrict__ gamma,
    const float* __restrict__ beta, float* __restrict__ out)
{
    int d = blockIdx.x * 256 + threadIdx.x;
    float v[8];
    float mean = 0.f;
#pragma unroll
    for (int b = 0; b < 8; b++) { v[b] = g[b * 768 + d]; mean += v[b]; }
    mean *= 0.125f;
    float var = 0.f;
#pragma unroll
    for (int b = 0; b < 8; b++) { float t = v[b] - mean; var += t * t; }
    var *= 0.125f;
    float inv = 1.0f / sqrtf(var + EPS_V);
#pragma unroll
    for (int b = 0; b < 8; b++)
        out[b * 768 + d] = gamma[d] * (v[b] - mean) * inv + beta[d];
}

// ---------------------------------------------------------------------------
extern "C" void kernel_launch(void* const* d_in, const int* in_sizes, int n_in,
                              void* d_out, int out_size, void* d_ws, size_t ws_size,
                              hipStream_t stream)
{
    const float* feature = (const float*)d_in[0];
    // d_in[1] = aspect: unused by the reference
    const int*   adj     = (const int*)d_in[2];
    const float* W0      = (const float*)d_in[3];
    const float* b0      = (const float*)d_in[4];
    const float* W1      = (const float*)d_in[5];
    const float* b1      = (const float*)d_in[6];
    const float* A1      = (const float*)d_in[7];
    const float* ab1     = (const float*)d_in[8];
    const float* A2      = (const float*)d_in[9];
    const float* ab2     = (const float*)d_in[10];
    const float* gamma   = (const float*)d_in[11];
    const float* beta    = (const float*)d_in[12];

    float* ws    = (float*)d_ws;
    float* h     = ws;                // 1024*768 = 786432
    float* s     = ws + 786432;       // 1024*128 = 131072
    float* p     = ws + 917504;       // 8*128*128 = 131072
    float* stats = ws + 1048576;      // 16
    float* g     = ws + 1048592;      // 8*768 = 6144

    float* out       = (float*)d_out;
    float* graph_out = out;           // (8,768)
    float* node_out  = out + 6144;    // (8,128,768); also layer-1 scratch

    const float* feat_in = feature;
    for (int layer = 0; layer < 2; layer++) {
        const float* W  = layer ? W1 : W0;
        const float* bb = layer ? b1 : b0;
        gemm_bias_k<<<dim3(12, 16), 256, 0, stream>>>(feat_in, W, bb, h, 768, 768);
        hipMemsetAsync(s, 0, 131072 * sizeof(float), stream);
        sproj_k<<<dim3(2, 16, 4), 256, 0, stream>>>(h, A1, s);
        score_k<<<dim3(8, 8), 256, 0, stream>>>(s, adj, ab1, A2, ab2, p);
        softmax_k<<<dim3(8), 1024, 0, stream>>>(p, stats);
        attn_gemm_k<<<dim3(12, 2, 8), 256, 0, stream>>>(p, h, stats, node_out);
        feat_in = node_out;
    }
    gsum_k<<<dim3(8, 3), 256, 0, stream>>>(node_out, g);
    bnorm_k<<<dim3(3), 256, 0, stream>>>(g, gamma, beta, graph_out);
}

// Round 3
// 253.362 us; speedup vs baseline: 1.9682x; 1.1360x over previous
//
#include <hip/hip_runtime.h>
#include <math.h>

#define NEG_V (-1e30f)
#define SLOPE_V 0.01f
#define EPS_V 1e-5f

typedef __attribute__((ext_vector_type(8))) short bs8;    // 8 bf16 (4 VGPRs)
typedef __attribute__((ext_vector_type(4))) float f32x4;  // mfma acc

// Split fp32 x into bf16 hi + bf16 lo (RNE both). x ≈ hi + lo with rel err ~2^-17.
__device__ __forceinline__ void split2(float x, unsigned short& hi, unsigned short& lo) {
    unsigned u = __float_as_uint(x);
    unsigned h = (u + 0x7FFFu + ((u >> 16) & 1u)) >> 16;
    hi = (unsigned short)h;
    float hf = __uint_as_float(h << 16);
    float l = x - hf;
    unsigned ul = __float_as_uint(l);
    lo = (unsigned short)((ul + 0x7FFFu + ((ul >> 16) & 1u)) >> 16);
}

// ---------------------------------------------------------------------------
// Shared split-bf16 MFMA mainloop. Block = 256 thr (4 waves), tile 64x64,
// wave tile 32x32 (2x2 mfma_f32_16x16x32_bf16 tiles, 3 mfma per tile: split).
// A: row-major [M][K]; if CVT_A, A is fp32 and split in-LDS during staging,
// else pre-split bf16 (Ahg/Alg). B: pre-split TRANSPOSED bf16 Bt[n][k]
// (mfma B-frag wants k-contiguous per n). LDS rows padded to 40 bf16 (80 B,
// odd 16B-granule stride -> uniform bank spread for b128 frag reads).
// Fragment layouts (verified, learn_hip m89/m91/m120):
//   A-frag: lane holds A[m=lane&15][k=(lane>>4)*8 + j]
//   B-frag: lane holds B[k=(lane>>4)*8 + j][n=lane&15]  (= Bt row read)
//   C/D:    col=lane&15, row=(lane>>4)*4 + reg
// ---------------------------------------------------------------------------
template<bool CVT_A>
__device__ __forceinline__ void mfma_loop(
    const float* __restrict__ Af,
    const unsigned short* __restrict__ Ahg, const unsigned short* __restrict__ Alg,
    int lda,
    const unsigned short* __restrict__ Bhg, const unsigned short* __restrict__ Blg,
    int ldb, int K, int row0, int col0,
    f32x4 (&acc)[2][2],
    unsigned short (*Ah)[40], unsigned short (*Al)[40],
    unsigned short (*Bh)[40], unsigned short (*Bl)[40])
{
    const int tid = threadIdx.x;
    const int lane = tid & 63, wid = tid >> 6;
    const int wm0 = (wid >> 1) * 32, wn0 = (wid & 1) * 32;
    const int lm = lane & 15, q = lane >> 4;
    const int sr = tid >> 2, sc = (tid & 3) * 8;

    for (int k0 = 0; k0 < K; k0 += 32) {
        if constexpr (CVT_A) {
            const float* ap = Af + (size_t)(row0 + sr) * lda + k0 + sc;
            float4 v0 = *(const float4*)ap;
            float4 v1 = *(const float4*)(ap + 4);
            bs8 sh, sl; unsigned short hh, ll;
            split2(v0.x, hh, ll); sh[0] = (short)hh; sl[0] = (short)ll;
            split2(v0.y, hh, ll); sh[1] = (short)hh; sl[1] = (short)ll;
            split2(v0.z, hh, ll); sh[2] = (short)hh; sl[2] = (short)ll;
            split2(v0.w, hh, ll); sh[3] = (short)hh; sl[3] = (short)ll;
            split2(v1.x, hh, ll); sh[4] = (short)hh; sl[4] = (short)ll;
            split2(v1.y, hh, ll); sh[5] = (short)hh; sl[5] = (short)ll;
            split2(v1.z, hh, ll); sh[6] = (short)hh; sl[6] = (short)ll;
            split2(v1.w, hh, ll); sh[7] = (short)hh; sl[7] = (short)ll;
            *(bs8*)&Ah[sr][sc] = sh;
            *(bs8*)&Al[sr][sc] = sl;
        } else {
            *(bs8*)&Ah[sr][sc] = *(const bs8*)(Ahg + (size_t)(row0 + sr) * lda + k0 + sc);
            *(bs8*)&Al[sr][sc] = *(const bs8*)(Alg + (size_t)(row0 + sr) * lda + k0 + sc);
        }
        *(bs8*)&Bh[sr][sc] = *(const bs8*)(Bhg + (size_t)(col0 + sr) * ldb + k0 + sc);
        *(bs8*)&Bl[sr][sc] = *(const bs8*)(Blg + (size_t)(col0 + sr) * ldb + k0 + sc);
        __syncthreads();

        bs8 a_h[2], a_l[2], b_h[2], b_l[2];
#pragma unroll
        for (int t = 0; t < 2; t++) {
            a_h[t] = *(bs8*)&Ah[wm0 + t * 16 + lm][q * 8];
            a_l[t] = *(bs8*)&Al[wm0 + t * 16 + lm][q * 8];
            b_h[t] = *(bs8*)&Bh[wn0 + t * 16 + lm][q * 8];
            b_l[t] = *(bs8*)&Bl[wn0 + t * 16 + lm][q * 8];
        }
#pragma unroll
        for (int mt = 0; mt < 2; mt++)
#pragma unroll
            for (int nt = 0; nt < 2; nt++) {
                acc[mt][nt] = __builtin_amdgcn_mfma_f32_16x16x32_bf16(a_h[mt], b_h[nt], acc[mt][nt], 0, 0, 0);
                acc[mt][nt] = __builtin_amdgcn_mfma_f32_16x16x32_bf16(a_h[mt], b_l[nt], acc[mt][nt], 0, 0, 0);
                acc[mt][nt] = __builtin_amdgcn_mfma_f32_16x16x32_bf16(a_l[mt], b_h[nt], acc[mt][nt], 0, 0, 0);
            }
        __syncthreads();
    }
}

// ---------------------------------------------------------------------------
// 64x64 fp32 tile -> transposed bf16 hi/lo (dst[n][k] = src[k][n]).
// ---------------------------------------------------------------------------
__device__ __forceinline__ void transpose_split_tile(
    const float* __restrict__ src, int src_ld,
    unsigned short* __restrict__ dh, unsigned short* __restrict__ dl, int dst_ld,
    unsigned short (*Th)[72], unsigned short (*Tl)[72])
{
    int tid = threadIdx.x;
    int r = tid >> 2;
    int cb = (tid & 3) * 16;
#pragma unroll
    for (int cc = 0; cc < 16; cc += 4) {
        float4 v = *(const float4*)(src + (size_t)r * src_ld + cb + cc);
        unsigned short hh, ll;
        split2(v.x, hh, ll); Th[cb + cc + 0][r] = hh; Tl[cb + cc + 0][r] = ll;
        split2(v.y, hh, ll); Th[cb + cc + 1][r] = hh; Tl[cb + cc + 1][r] = ll;
        split2(v.z, hh, ll); Th[cb + cc + 2][r] = hh; Tl[cb + cc + 2][r] = ll;
        split2(v.w, hh, ll); Th[cb + cc + 3][r] = hh; Tl[cb + cc + 3][r] = ll;
    }
    __syncthreads();
    int n = tid >> 2, ch = (tid & 3) * 8;
    *(bs8*)(dh + (size_t)n * dst_ld + ch)      = *(bs8*)&Th[n][ch];
    *(bs8*)(dh + (size_t)n * dst_ld + ch + 32) = *(bs8*)&Th[n][ch + 32];
    *(bs8*)(dl + (size_t)n * dst_ld + ch)      = *(bs8*)&Tl[n][ch];
    *(bs8*)(dl + (size_t)n * dst_ld + ch + 32) = *(bs8*)&Tl[n][ch + 32];
}

// Prep: W0,W1 (768x768) and A1 (1536x64) -> transposed split bf16. grid 312.
__global__ __launch_bounds__(256) void wsplit_k(
    const float* __restrict__ W0, const float* __restrict__ W1,
    const float* __restrict__ A1,
    unsigned short* Wt0h, unsigned short* Wt0l,
    unsigned short* Wt1h, unsigned short* Wt1l,
    unsigned short* A1th, unsigned short* A1tl)
{
    __shared__ unsigned short Th[64][72], Tl[64][72];
    int id = blockIdx.x;
    if (id < 144) {
        int kt = id / 12, nt = id % 12;
        transpose_split_tile(W0 + (size_t)(kt * 64) * 768 + nt * 64, 768,
                             Wt0h + (size_t)(nt * 64) * 768 + kt * 64,
                             Wt0l + (size_t)(nt * 64) * 768 + kt * 64, 768, Th, Tl);
    } else if (id < 288) {
        int r = id - 144, kt = r / 12, nt = r % 12;
        transpose_split_tile(W1 + (size_t)(kt * 64) * 768 + nt * 64, 768,
                             Wt1h + (size_t)(nt * 64) * 768 + kt * 64,
                             Wt1l + (size_t)(nt * 64) * 768 + kt * 64, 768, Th, Tl);
    } else {
        int r = id - 288, kt = r >> 1, nh = r & 1;   // nh: 0=src half, 1=tgt half
        transpose_split_tile(A1 + (size_t)(nh * 768 + kt * 64) * 64, 64,
                             A1th + (size_t)(nh * 64) * 768 + kt * 64,
                             A1tl + (size_t)(nh * 64) * 768 + kt * 64, 768, Th, Tl);
    }
}

// Per layer: h (1024x768 fp32) -> ht[b][d][j] bf16 hi/lo (attn B-operand).
// grid (12 n-tiles, 2 k-tiles, 8 b).
__global__ __launch_bounds__(256) void htrans_k(
    const float* __restrict__ h, unsigned short* hth, unsigned short* htl)
{
    __shared__ unsigned short Th[64][72], Tl[64][72];
    int nt = blockIdx.x, kt = blockIdx.y, b = blockIdx.z;
    const float* src = h + (size_t)(b * 128 + kt * 64) * 768 + nt * 64;
    size_t doff = ((size_t)b * 768 + nt * 64) * 128 + kt * 64;
    transpose_split_tile(src, 768, hth + doff, htl + doff, 128, Th, Tl);
}

// ---------------------------------------------------------------------------
// h = A @ W + bias. A fp32 (split in-loop), B = Wt pre-split. grid (12,16).
// ---------------------------------------------------------------------------
__global__ __launch_bounds__(256) void gemm_mfma_bias_k(
    const float* __restrict__ A,
    const unsigned short* __restrict__ Bth, const unsigned short* __restrict__ Btl,
    const float* __restrict__ bias, float* __restrict__ C)
{
    __shared__ unsigned short Ah[64][40], Al[64][40], Bh[64][40], Bl[64][40];
    int row0 = blockIdx.y * 64, col0 = blockIdx.x * 64;
    f32x4 acc[2][2] = {};
    mfma_loop<true>(A, nullptr, nullptr, 768, Bth, Btl, 768, 768,
                    row0, col0, acc, Ah, Al, Bh, Bl);
    int lane = threadIdx.x & 63, wid = threadIdx.x >> 6;
    int wm0 = (wid >> 1) * 32, wn0 = (wid & 1) * 32;
    int lm = lane & 15, q = lane >> 4;
#pragma unroll
    for (int mt = 0; mt < 2; mt++)
#pragma unroll
        for (int nt = 0; nt < 2; nt++) {
            int c = col0 + wn0 + nt * 16 + lm;
            float bv = bias[c];
#pragma unroll
            for (int i = 0; i < 4; i++) {
                int r = row0 + wm0 + mt * 16 + q * 4 + i;
                C[(size_t)r * 768 + c] = acc[mt][nt][i] + bv;
            }
        }
}

// s = h @ A1t (both halves): M=1024, N=128, K=768. grid (2,16).
__global__ __launch_bounds__(256) void sproj_mfma_k(
    const float* __restrict__ h,
    const unsigned short* __restrict__ A1th, const unsigned short* __restrict__ A1tl,
    float* __restrict__ s)
{
    __shared__ unsigned short Ah[64][40], Al[64][40], Bh[64][40], Bl[64][40];
    int row0 = blockIdx.y * 64, col0 = blockIdx.x * 64;
    f32x4 acc[2][2] = {};
    mfma_loop<true>(h, nullptr, nullptr, 768, A1th, A1tl, 768, 768,
                    row0, col0, acc, Ah, Al, Bh, Bl);
    int lane = threadIdx.x & 63, wid = threadIdx.x >> 6;
    int wm0 = (wid >> 1) * 32, wn0 = (wid & 1) * 32;
    int lm = lane & 15, q = lane >> 4;
#pragma unroll
    for (int mt = 0; mt < 2; mt++)
#pragma unroll
        for (int nt = 0; nt < 2; nt++) {
            int c = col0 + wn0 + nt * 16 + lm;
#pragma unroll
            for (int i = 0; i < 4; i++) {
                int r = row0 + wm0 + mt * 16 + q * 4 + i;
                s[(size_t)r * 128 + c] = acc[mt][nt][i];
            }
        }
}

// node[b] = (1/sum_b) * P[b] @ h[b]: per-batch M=128, N=768, K=128.
// A = p pre-split (softmax epilogue), B = ht pre-split. grid (12,2,8).
__global__ __launch_bounds__(256) void attn_mfma_k(
    const unsigned short* __restrict__ ph, const unsigned short* __restrict__ pl,
    const unsigned short* __restrict__ hth, const unsigned short* __restrict__ htl,
    const float* __restrict__ stats, float* __restrict__ node)
{
    __shared__ unsigned short Ah[64][40], Al[64][40], Bh[64][40], Bl[64][40];
    int b = blockIdx.z;
    int row0 = blockIdx.y * 64, col0 = blockIdx.x * 64;
    f32x4 acc[2][2] = {};
    mfma_loop<false>(nullptr, ph + (size_t)b * 16384, pl + (size_t)b * 16384, 128,
                     hth + (size_t)b * 98304, htl + (size_t)b * 98304, 128, 128,
                     row0, col0, acc, Ah, Al, Bh, Bl);
    float alpha = 1.0f / stats[b];
    float* C = node + (size_t)b * 98304;
    int lane = threadIdx.x & 63, wid = threadIdx.x >> 6;
    int wm0 = (wid >> 1) * 32, wn0 = (wid & 1) * 32;
    int lm = lane & 15, q = lane >> 4;
#pragma unroll
    for (int mt = 0; mt < 2; mt++)
#pragma unroll
        for (int nt = 0; nt < 2; nt++) {
            int c = col0 + wn0 + nt * 16 + lm;
#pragma unroll
            for (int i = 0; i < 4; i++) {
                int r = row0 + wm0 + mt * 16 + q * 4 + i;
                C[(size_t)r * 768 + c] = acc[mt][nt][i] * alpha;
            }
        }
}

// ---------------------------------------------------------------------------
// Masked logits, register-tiled: thread owns 2i x 4j (j interleaved by 32 to
// keep st-column reads conflict-free). grid (8 i-tiles, 8 b), block 256.
// ---------------------------------------------------------------------------
__global__ __launch_bounds__(256) void score_k(
    const float* __restrict__ s, const int* __restrict__ adj,
    const float* __restrict__ ab1, const float* __restrict__ A2,
    const float* __restrict__ ab2, float* __restrict__ p)
{
    __shared__ float ss[16][65];   // s_src rows + ab1 folded
    __shared__ float st[128][65];  // s_tgt rows
    __shared__ float a2s[64];
    int b = blockIdx.y, i0 = blockIdx.x * 16, tid = threadIdx.x;
    for (int idx = tid; idx < 8192; idx += 256) {
        int j = idx >> 6, hh = idx & 63;
        st[j][hh] = s[(size_t)(b * 128 + j) * 128 + 64 + hh];
    }
    for (int idx = tid; idx < 1024; idx += 256) {
        int i = idx >> 6, hh = idx & 63;
        ss[i][hh] = s[(size_t)(b * 128 + i0 + i) * 128 + hh] + ab1[hh];
    }
    if (tid < 64) a2s[tid] = A2[tid];
    __syncthreads();
    float ab2v = ab2[0];
    int it = tid >> 5;   // 0..7 -> i pair
    int jt = tid & 31;   // j = jt + 32*e
    float ev[2][4] = {};
    for (int hh = 0; hh < 64; hh++) {
        float a0 = ss[it * 2 + 0][hh];
        float a1 = ss[it * 2 + 1][hh];
        float c = a2s[hh];
#pragma unroll
        for (int e = 0; e < 4; e++) {
            float bb = st[jt + 32 * e][hh];
            ev[0][e] = fmaf(fmaxf(a0 + bb, 0.f), c, ev[0][e]);
            ev[1][e] = fmaf(fmaxf(a1 + bb, 0.f), c, ev[1][e]);
        }
    }
#pragma unroll
    for (int ii = 0; ii < 2; ii++)
#pragma unroll
        for (int e = 0; e < 4; e++) {
            int i = i0 + it * 2 + ii;
            int j = jt + 32 * e;
            float eev = ev[ii][e] + ab2v;
            eev = (eev > 0.f) ? eev : SLOPE_V * eev;
            size_t off = (size_t)b * 16384 + (size_t)i * 128 + j;
            p[off] = adj[off] ? eev : NEG_V;
        }
}

// ---------------------------------------------------------------------------
// Per-batch flattened softmax; writes UNnormalized exp split to bf16 hi/lo,
// sum to stats (1/sum applied in attn epilogue). grid 8, block 1024.
// ---------------------------------------------------------------------------
__global__ __launch_bounds__(1024) void softmax_k(
    const float* __restrict__ p, unsigned short* __restrict__ ph,
    unsigned short* __restrict__ pl, float* __restrict__ stats)
{
    int b = blockIdx.x, tid = threadIdx.x;
    const float* pb = p + (size_t)b * 16384;
    __shared__ float red[1024];
    float mx = -3.4e38f;
    for (int i = tid; i < 16384; i += 1024) mx = fmaxf(mx, pb[i]);
    red[tid] = mx;
    __syncthreads();
    for (int sft = 512; sft > 0; sft >>= 1) {
        if (tid < sft) red[tid] = fmaxf(red[tid], red[tid + sft]);
        __syncthreads();
    }
    mx = red[0];
    __syncthreads();
    float sum = 0.f;
    for (int i = tid; i < 16384; i += 1024) {
        float v = expf(pb[i] - mx);
        unsigned short hh, ll;
        split2(v, hh, ll);
        ph[(size_t)b * 16384 + i] = hh;
        pl[(size_t)b * 16384 + i] = ll;
        sum += v;
    }
    red[tid] = sum;
    __syncthreads();
    for (int sft = 512; sft > 0; sft >>= 1) {
        if (tid < sft) red[tid] += red[tid + sft];
        __syncthreads();
    }
    if (tid == 0) stats[b] = red[0];
}

// ---------------------------------------------------------------------------
// Fused graph-sum + batch-norm over batch axis. grid 3, block 256.
// ---------------------------------------------------------------------------
__global__ __launch_bounds__(256) void gsum_bnorm_k(
    const float* __restrict__ node, const float* __restrict__ gamma,
    const float* __restrict__ beta, float* __restrict__ out)
{
    int d = blockIdx.x * 256 + threadIdx.x;
    float v[8] = {};
    for (int i = 0; i < 128; i++) {
#pragma unroll
        for (int b = 0; b < 8; b++)
            v[b] += node[(size_t)(b * 128 + i) * 768 + d];
    }
    float mean = 0.f;
#pragma unroll
    for (int b = 0; b < 8; b++) mean += v[b];
    mean *= 0.125f;
    float var = 0.f;
#pragma unroll
    for (int b = 0; b < 8; b++) { float t = v[b] - mean; var += t * t; }
    var *= 0.125f;
    float inv = 1.0f / sqrtf(var + EPS_V);
#pragma unroll
    for (int b = 0; b < 8; b++)
        out[b * 768 + d] = gamma[d] * (v[b] - mean) * inv + beta[d];
}

// ---------------------------------------------------------------------------
extern "C" void kernel_launch(void* const* d_in, const int* in_sizes, int n_in,
                              void* d_out, int out_size, void* d_ws, size_t ws_size,
                              hipStream_t stream)
{
    const float* feature = (const float*)d_in[0];
    // d_in[1] = aspect: unused by the reference
    const int*   adj     = (const int*)d_in[2];
    const float* W0      = (const float*)d_in[3];
    const float* b0      = (const float*)d_in[4];
    const float* W1      = (const float*)d_in[5];
    const float* b1      = (const float*)d_in[6];
    const float* A1      = (const float*)d_in[7];
    const float* ab1     = (const float*)d_in[8];
    const float* A2      = (const float*)d_in[9];
    const float* ab2     = (const float*)d_in[10];
    const float* gamma   = (const float*)d_in[11];
    const float* beta    = (const float*)d_in[12];

    float* ws    = (float*)d_ws;
    float* h     = ws;               // 786432 f
    float* s     = ws + 786432;      // 131072 f
    float* p     = ws + 917504;      // 131072 f
    float* stats = ws + 1048576;     // 16 f
    unsigned short* u = (unsigned short*)(ws + 1048592);  // 16B-aligned
    unsigned short* Wt0h = u;                  // 589824 each
    unsigned short* Wt0l = Wt0h + 589824;
    unsigned short* Wt1h = Wt0l + 589824;
    unsigned short* Wt1l = Wt1h + 589824;
    unsigned short* A1th = Wt1l + 589824;      // 98304 each
    unsigned short* A1tl = A1th + 98304;
    unsigned short* hth  = A1tl + 98304;       // 786432 each
    unsigned short* htl  = hth + 786432;
    unsigned short* ph   = htl + 786432;       // 131072 each
    unsigned short* pl   = ph + 131072;
    // total ws use: ~12.4 MiB

    float* out       = (float*)d_out;
    float* graph_out = out;          // (8,768)
    float* node_out  = out + 6144;   // (8,128,768); also layer-1 scratch

    wsplit_k<<<312, 256, 0, stream>>>(W0, W1, A1, Wt0h, Wt0l, Wt1h, Wt1l, A1th, A1tl);

    const float* feat_in = feature;
    for (int layer = 0; layer < 2; layer++) {
        const unsigned short* Wth = layer ? Wt1h : Wt0h;
        const unsigned short* Wtl = layer ? Wt1l : Wt0l;
        const float* bb = layer ? b1 : b0;
        gemm_mfma_bias_k<<<dim3(12, 16), 256, 0, stream>>>(feat_in, Wth, Wtl, bb, h);
        htrans_k<<<dim3(12, 2, 8), 256, 0, stream>>>(h, hth, htl);
        sproj_mfma_k<<<dim3(2, 16), 256, 0, stream>>>(h, A1th, A1tl, s);
        score_k<<<dim3(8, 8), 256, 0, stream>>>(s, adj, ab1, A2, ab2, p);
        softmax_k<<<8, 1024, 0, stream>>>(p, ph, pl, stats);
        attn_mfma_k<<<dim3(12, 2, 8), 256, 0, stream>>>(ph, pl, hth, htl, stats, node_out);
        feat_in = node_out;
    }
    gsum_bnorm_k<<<3, 256, 0, stream>>>(node_out, gamma, beta, graph_out);
}

// Round 4
// 202.779 us; speedup vs baseline: 2.4592x; 1.2494x over previous
//
#include <hip/hip_runtime.h>
#include <math.h>

#define NEG_V (-1e30f)
#define SLOPE_V 0.01f
#define EPS_V 1e-5f

typedef __attribute__((ext_vector_type(8))) short bs8;    // 8 bf16 (4 VGPRs)
typedef __attribute__((ext_vector_type(4))) float f32x4;  // mfma acc

// Split fp32 x into bf16 hi + bf16 lo (RNE both). x ≈ hi + lo, rel err ~2^-17.
__device__ __forceinline__ void split2(float x, unsigned short& hi, unsigned short& lo) {
    unsigned u = __float_as_uint(x);
    unsigned h = (u + 0x7FFFu + ((u >> 16) & 1u)) >> 16;
    hi = (unsigned short)h;
    float hf = __uint_as_float(h << 16);
    float l = x - hf;
    unsigned ul = __float_as_uint(l);
    lo = (unsigned short)((ul + 0x7FFFu + ((ul >> 16) & 1u)) >> 16);
}

// ---------------------------------------------------------------------------
// Pure-bf16 split MFMA mainloop. Block = 256 thr (4 waves), tile 64x64,
// wave tile 32x32 (2x2 mfma_f32_16x16x32_bf16, 3 mfma per tile: hi*hi,
// hi*lo, lo*hi). A pre-split row-major [M][K]; B pre-split TRANSPOSED
// Bt[n][k]. LDS rows padded to 40 bf16 (80 B).
// Fragment layouts (verified, learn_hip m89/m91/m120):
//   A-frag: lane holds A[m=lane&15][k=(lane>>4)*8 + j]
//   B-frag: lane holds B[k=(lane>>4)*8 + j][n=lane&15]  (= Bt row read)
//   C/D:    col=lane&15, row=(lane>>4)*4 + reg
// ---------------------------------------------------------------------------
__device__ __forceinline__ void mfma_loop(
    const unsigned short* __restrict__ Ahg, const unsigned short* __restrict__ Alg,
    int lda,
    const unsigned short* __restrict__ Bhg, const unsigned short* __restrict__ Blg,
    int ldb, int K, int row0, int col0,
    f32x4 (&acc)[2][2],
    unsigned short (*Ah)[40], unsigned short (*Al)[40],
    unsigned short (*Bh)[40], unsigned short (*Bl)[40])
{
    const int tid = threadIdx.x;
    const int lane = tid & 63, wid = tid >> 6;
    const int wm0 = (wid >> 1) * 32, wn0 = (wid & 1) * 32;
    const int lm = lane & 15, q = lane >> 4;
    const int sr = tid >> 2, sc = (tid & 3) * 8;

    for (int k0 = 0; k0 < K; k0 += 32) {
        *(bs8*)&Ah[sr][sc] = *(const bs8*)(Ahg + (size_t)(row0 + sr) * lda + k0 + sc);
        *(bs8*)&Al[sr][sc] = *(const bs8*)(Alg + (size_t)(row0 + sr) * lda + k0 + sc);
        *(bs8*)&Bh[sr][sc] = *(const bs8*)(Bhg + (size_t)(col0 + sr) * ldb + k0 + sc);
        *(bs8*)&Bl[sr][sc] = *(const bs8*)(Blg + (size_t)(col0 + sr) * ldb + k0 + sc);
        __syncthreads();

        bs8 a_h[2], a_l[2], b_h[2], b_l[2];
#pragma unroll
        for (int t = 0; t < 2; t++) {
            a_h[t] = *(bs8*)&Ah[wm0 + t * 16 + lm][q * 8];
            a_l[t] = *(bs8*)&Al[wm0 + t * 16 + lm][q * 8];
            b_h[t] = *(bs8*)&Bh[wn0 + t * 16 + lm][q * 8];
            b_l[t] = *(bs8*)&Bl[wn0 + t * 16 + lm][q * 8];
        }
#pragma unroll
        for (int mt = 0; mt < 2; mt++)
#pragma unroll
            for (int nt = 0; nt < 2; nt++) {
                acc[mt][nt] = __builtin_amdgcn_mfma_f32_16x16x32_bf16(a_h[mt], b_h[nt], acc[mt][nt], 0, 0, 0);
                acc[mt][nt] = __builtin_amdgcn_mfma_f32_16x16x32_bf16(a_h[mt], b_l[nt], acc[mt][nt], 0, 0, 0);
                acc[mt][nt] = __builtin_amdgcn_mfma_f32_16x16x32_bf16(a_l[mt], b_h[nt], acc[mt][nt], 0, 0, 0);
            }
        __syncthreads();
    }
}

// ---------------------------------------------------------------------------
// 64x64 fp32 tile -> transposed bf16 hi/lo (dst[n][k] = src[k][n]).
// ---------------------------------------------------------------------------
__device__ __forceinline__ void transpose_split_tile(
    const float* __restrict__ src, int src_ld,
    unsigned short* __restrict__ dh, unsigned short* __restrict__ dl, int dst_ld,
    unsigned short (*Th)[72], unsigned short (*Tl)[72])
{
    int tid = threadIdx.x;
    int r = tid >> 2;
    int cb = (tid & 3) * 16;
#pragma unroll
    for (int cc = 0; cc < 16; cc += 4) {
        float4 v = *(const float4*)(src + (size_t)r * src_ld + cb + cc);
        unsigned short hh, ll;
        split2(v.x, hh, ll); Th[cb + cc + 0][r] = hh; Tl[cb + cc + 0][r] = ll;
        split2(v.y, hh, ll); Th[cb + cc + 1][r] = hh; Tl[cb + cc + 1][r] = ll;
        split2(v.z, hh, ll); Th[cb + cc + 2][r] = hh; Tl[cb + cc + 2][r] = ll;
        split2(v.w, hh, ll); Th[cb + cc + 3][r] = hh; Tl[cb + cc + 3][r] = ll;
    }
    __syncthreads();
    int n = tid >> 2, ch = (tid & 3) * 8;
    *(bs8*)(dh + (size_t)n * dst_ld + ch)      = *(bs8*)&Th[n][ch];
    *(bs8*)(dh + (size_t)n * dst_ld + ch + 32) = *(bs8*)&Th[n][ch + 32];
    *(bs8*)(dl + (size_t)n * dst_ld + ch)      = *(bs8*)&Tl[n][ch];
    *(bs8*)(dl + (size_t)n * dst_ld + ch + 32) = *(bs8*)&Tl[n][ch + 32];
}

// ---------------------------------------------------------------------------
// Prep: W0,W1 -> Wt (transposed split); A1 -> A1t (transposed split);
// feature -> fh/fl (row-major split). grid 504.
// ---------------------------------------------------------------------------
__global__ __launch_bounds__(256) void prep_k(
    const float* __restrict__ W0, const float* __restrict__ W1,
    const float* __restrict__ A1, const float* __restrict__ feature,
    unsigned short* Wt0h, unsigned short* Wt0l,
    unsigned short* Wt1h, unsigned short* Wt1l,
    unsigned short* A1th, unsigned short* A1tl,
    unsigned short* fh, unsigned short* fl)
{
    __shared__ unsigned short Th[64][72], Tl[64][72];
    int id = blockIdx.x;
    if (id < 144) {
        int kt = id / 12, nt = id % 12;
        transpose_split_tile(W0 + (size_t)(kt * 64) * 768 + nt * 64, 768,
                             Wt0h + (size_t)(nt * 64) * 768 + kt * 64,
                             Wt0l + (size_t)(nt * 64) * 768 + kt * 64, 768, Th, Tl);
    } else if (id < 288) {
        int r = id - 144, kt = r / 12, nt = r % 12;
        transpose_split_tile(W1 + (size_t)(kt * 64) * 768 + nt * 64, 768,
                             Wt1h + (size_t)(nt * 64) * 768 + kt * 64,
                             Wt1l + (size_t)(nt * 64) * 768 + kt * 64, 768, Th, Tl);
    } else if (id < 312) {
        int r = id - 288, kt = r >> 1, nh = r & 1;
        transpose_split_tile(A1 + (size_t)(nh * 768 + kt * 64) * 64, 64,
                             A1th + (size_t)(nh * 64) * 768 + kt * 64,
                             A1tl + (size_t)(nh * 64) * 768 + kt * 64, 768, Th, Tl);
    } else {
        // feature split: 192 blocks x 4096 elems, 16 per thread
        size_t base = (size_t)(id - 312) * 4096 + threadIdx.x * 16;
        bs8 sh0, sh1, sl0, sl1;
        unsigned short hh, ll;
#pragma unroll
        for (int g = 0; g < 2; g++) {
            bs8& sh = g ? sh1 : sh0;
            bs8& sl = g ? sl1 : sl0;
#pragma unroll
            for (int cc = 0; cc < 8; cc += 4) {
                float4 v = *(const float4*)(feature + base + g * 8 + cc);
                split2(v.x, hh, ll); sh[cc + 0] = (short)hh; sl[cc + 0] = (short)ll;
                split2(v.y, hh, ll); sh[cc + 1] = (short)hh; sl[cc + 1] = (short)ll;
                split2(v.z, hh, ll); sh[cc + 2] = (short)hh; sl[cc + 2] = (short)ll;
                split2(v.w, hh, ll); sh[cc + 3] = (short)hh; sl[cc + 3] = (short)ll;
            }
        }
        *(bs8*)(fh + base) = sh0; *(bs8*)(fh + base + 8) = sh1;
        *(bs8*)(fl + base) = sl0; *(bs8*)(fl + base + 8) = sl1;
    }
}

// ---------------------------------------------------------------------------
// h = A @ W + bias; outputs SPLIT row-major (hh/hl for sproj) and SPLIT
// TRANSPOSED per-batch (hth/htl for attn B). No fp32 h. grid (12,16).
// ---------------------------------------------------------------------------
__global__ __launch_bounds__(256) void gemm_mfma_bias_k(
    const unsigned short* __restrict__ Ahg, const unsigned short* __restrict__ Alg,
    const unsigned short* __restrict__ Bth, const unsigned short* __restrict__ Btl,
    const float* __restrict__ bias,
    unsigned short* __restrict__ hh, unsigned short* __restrict__ hl,
    unsigned short* __restrict__ hth, unsigned short* __restrict__ htl)
{
    __shared__ unsigned short smem[4][64][40];   // 10240 shorts
    int row0 = blockIdx.y * 64, col0 = blockIdx.x * 64;
    f32x4 acc[2][2] = {};
    mfma_loop(Ahg, Alg, 768, Bth, Btl, 768, 768, row0, col0, acc,
              smem[0], smem[1], smem[2], smem[3]);
    __syncthreads();
    // stage tile (with bias) as split hi/lo in LDS, pad 69 (conflict-free col reads)
    unsigned short* flat = &smem[0][0][0];
    unsigned short (*Hi)[69] = (unsigned short(*)[69])flat;            // 4416 shorts
    unsigned short (*Lo)[69] = (unsigned short(*)[69])(flat + 4416);   // total 8832 <= 10240
    int tid = threadIdx.x, lane = tid & 63, wid = tid >> 6;
    int wm0 = (wid >> 1) * 32, wn0 = (wid & 1) * 32;
    int lm = lane & 15, q = lane >> 4;
#pragma unroll
    for (int mt = 0; mt < 2; mt++)
#pragma unroll
        for (int nt = 0; nt < 2; nt++) {
            int c = wn0 + nt * 16 + lm;
            float bv = bias[col0 + c];
#pragma unroll
            for (int i = 0; i < 4; i++) {
                int r = wm0 + mt * 16 + q * 4 + i;
                unsigned short hv, lv;
                split2(acc[mt][nt][i] + bv, hv, lv);
                Hi[r][c] = hv; Lo[r][c] = lv;
            }
        }
    __syncthreads();
    // row-major split out
    {
        int r = tid >> 2, cq = (tid & 3) * 16;
        bs8 vh0, vh1, vl0, vl1;
#pragma unroll
        for (int e = 0; e < 8; e++) {
            vh0[e] = Hi[r][cq + e];     vh1[e] = Hi[r][cq + 8 + e];
            vl0[e] = Lo[r][cq + e];     vl1[e] = Lo[r][cq + 8 + e];
        }
        size_t ro = (size_t)(row0 + r) * 768 + col0 + cq;
        *(bs8*)(hh + ro) = vh0; *(bs8*)(hh + ro + 8) = vh1;
        *(bs8*)(hl + ro) = vl0; *(bs8*)(hl + ro + 8) = vl1;
    }
    // transposed split out: hth[b][d][k], ld 128, per-batch base b*98304
    {
        int d = tid >> 2, kq = (tid & 3) * 16;
        int b = row0 >> 7, kb = row0 & 127;
        bs8 th0, th1, tl0, tl1;
#pragma unroll
        for (int e = 0; e < 8; e++) {
            th0[e] = Hi[kq + e][d];     th1[e] = Hi[kq + 8 + e][d];
            tl0[e] = Lo[kq + e][d];     tl1[e] = Lo[kq + 8 + e][d];
        }
        size_t to = ((size_t)b * 768 + col0 + d) * 128 + kb + kq;
        *(bs8*)(hth + to) = th0; *(bs8*)(hth + to + 8) = th1;
        *(bs8*)(htl + to) = tl0; *(bs8*)(htl + to + 8) = tl1;
    }
}

// ---------------------------------------------------------------------------
// sproj: s_part[kc] = h[:, kc*384:+384] @ A1t chunk. grid (2,16,2).
// Partials summed inside score_k. No zero-init needed.
// ---------------------------------------------------------------------------
__global__ __launch_bounds__(256) void sproj_mfma_k(
    const unsigned short* __restrict__ hh, const unsigned short* __restrict__ hl,
    const unsigned short* __restrict__ A1th, const unsigned short* __restrict__ A1tl,
    float* __restrict__ s)
{
    __shared__ unsigned short smem[4][64][40];
    int col0 = blockIdx.x * 64, row0 = blockIdx.y * 64, kc = blockIdx.z;
    f32x4 acc[2][2] = {};
    mfma_loop(hh + kc * 384, hl + kc * 384, 768,
              A1th + kc * 384, A1tl + kc * 384, 768,
              384, row0, col0, acc, smem[0], smem[1], smem[2], smem[3]);
    float* sp = s + (size_t)kc * 131072;
    int lane = threadIdx.x & 63, wid = threadIdx.x >> 6;
    int wm0 = (wid >> 1) * 32, wn0 = (wid & 1) * 32;
    int lm = lane & 15, q = lane >> 4;
#pragma unroll
    for (int mt = 0; mt < 2; mt++)
#pragma unroll
        for (int nt = 0; nt < 2; nt++) {
            int c = col0 + wn0 + nt * 16 + lm;
#pragma unroll
            for (int i = 0; i < 4; i++) {
                int r = row0 + wm0 + mt * 16 + q * 4 + i;
                sp[(size_t)r * 128 + c] = acc[mt][nt][i];
            }
        }
}

// ---------------------------------------------------------------------------
// Masked logits from partials. grid (8 i-tiles, 8 b), block 256.
// ---------------------------------------------------------------------------
__global__ __launch_bounds__(256) void score_k(
    const float* __restrict__ s, const int* __restrict__ adj,
    const float* __restrict__ ab1, const float* __restrict__ A2,
    const float* __restrict__ ab2, float* __restrict__ p)
{
    __shared__ float ss[16][65];   // s_src rows + ab1 folded
    __shared__ float st[128][65];  // s_tgt rows
    __shared__ float a2s[64];
    int b = blockIdx.y, i0 = blockIdx.x * 16, tid = threadIdx.x;
    for (int idx = tid; idx < 8192; idx += 256) {
        int j = idx >> 6, hh = idx & 63;
        size_t off = (size_t)(b * 128 + j) * 128 + 64 + hh;
        st[j][hh] = s[off] + s[off + 131072];
    }
    for (int idx = tid; idx < 1024; idx += 256) {
        int i = idx >> 6, hh = idx & 63;
        size_t off = (size_t)(b * 128 + i0 + i) * 128 + hh;
        ss[i][hh] = s[off] + s[off + 131072] + ab1[hh];
    }
    if (tid < 64) a2s[tid] = A2[tid];
    __syncthreads();
    float ab2v = ab2[0];
    int it = tid >> 5;   // i pair
    int jt = tid & 31;   // j = jt + 32*e
    float ev[2][4] = {};
    for (int hh = 0; hh < 64; hh++) {
        float a0 = ss[it * 2 + 0][hh];
        float a1 = ss[it * 2 + 1][hh];
        float c = a2s[hh];
#pragma unroll
        for (int e = 0; e < 4; e++) {
            float bb = st[jt + 32 * e][hh];
            ev[0][e] = fmaf(fmaxf(a0 + bb, 0.f), c, ev[0][e]);
            ev[1][e] = fmaf(fmaxf(a1 + bb, 0.f), c, ev[1][e]);
        }
    }
#pragma unroll
    for (int ii = 0; ii < 2; ii++)
#pragma unroll
        for (int e = 0; e < 4; e++) {
            int i = i0 + it * 2 + ii;
            int j = jt + 32 * e;
            float eev = ev[ii][e] + ab2v;
            eev = (eev > 0.f) ? eev : SLOPE_V * eev;
            size_t off = (size_t)b * 16384 + (size_t)i * 128 + j;
            p[off] = adj[off] ? eev : NEG_V;
        }
}

// ---------------------------------------------------------------------------
// Per-batch flattened softmax; writes UNnormalized exp split bf16 hi/lo;
// 1/sum applied in attn epilogue. grid 8, block 1024.
// ---------------------------------------------------------------------------
__global__ __launch_bounds__(1024) void softmax_k(
    const float* __restrict__ p, unsigned short* __restrict__ ph,
    unsigned short* __restrict__ pl, float* __restrict__ stats)
{
    int b = blockIdx.x, tid = threadIdx.x;
    const float* pb = p + (size_t)b * 16384;
    __shared__ float red[1024];
    float mx = -3.4e38f;
    for (int i = tid; i < 16384; i += 1024) mx = fmaxf(mx, pb[i]);
    red[tid] = mx;
    __syncthreads();
    for (int sft = 512; sft > 0; sft >>= 1) {
        if (tid < sft) red[tid] = fmaxf(red[tid], red[tid + sft]);
        __syncthreads();
    }
    mx = red[0];
    __syncthreads();
    float sum = 0.f;
    for (int i = tid; i < 16384; i += 1024) {
        float v = expf(pb[i] - mx);
        unsigned short hv, lv;
        split2(v, hv, lv);
        ph[(size_t)b * 16384 + i] = hv;
        pl[(size_t)b * 16384 + i] = lv;
        sum += v;
    }
    red[tid] = sum;
    __syncthreads();
    for (int sft = 512; sft > 0; sft >>= 1) {
        if (tid < sft) red[tid] += red[tid + sft];
        __syncthreads();
    }
    if (tid == 0) stats[b] = red[0];
}

// ---------------------------------------------------------------------------
// node[b] = (1/sum_b) * P[b] @ h[b]; outputs fp32 node AND split nodeh/nodel
// (next layer's gemm A). grid (12,2,8).
// ---------------------------------------------------------------------------
__global__ __launch_bounds__(256) void attn_mfma_k(
    const unsigned short* __restrict__ ph, const unsigned short* __restrict__ pl,
    const unsigned short* __restrict__ hth, const unsigned short* __restrict__ htl,
    const float* __restrict__ stats, float* __restrict__ node,
    unsigned short* __restrict__ nodeh, unsigned short* __restrict__ nodel)
{
    __shared__ unsigned short smem[4][64][40];
    int b = blockIdx.z;
    int row0 = blockIdx.y * 64, col0 = blockIdx.x * 64;
    f32x4 acc[2][2] = {};
    mfma_loop(ph + (size_t)b * 16384, pl + (size_t)b * 16384, 128,
              hth + (size_t)b * 98304, htl + (size_t)b * 98304, 128, 128,
              row0, col0, acc, smem[0], smem[1], smem[2], smem[3]);
    __syncthreads();
    float alpha = 1.0f / stats[b];
    float* C = node + (size_t)b * 98304;
    unsigned short* flat = &smem[0][0][0];
    unsigned short (*Hi)[69] = (unsigned short(*)[69])flat;
    unsigned short (*Lo)[69] = (unsigned short(*)[69])(flat + 4416);
    int tid = threadIdx.x, lane = tid & 63, wid = tid >> 6;
    int wm0 = (wid >> 1) * 32, wn0 = (wid & 1) * 32;
    int lm = lane & 15, q = lane >> 4;
#pragma unroll
    for (int mt = 0; mt < 2; mt++)
#pragma unroll
        for (int nt = 0; nt < 2; nt++) {
            int c = wn0 + nt * 16 + lm;
#pragma unroll
            for (int i = 0; i < 4; i++) {
                int r = wm0 + mt * 16 + q * 4 + i;
                float v = acc[mt][nt][i] * alpha;
                C[(size_t)(row0 + r) * 768 + col0 + c] = v;
                unsigned short hv, lv;
                split2(v, hv, lv);
                Hi[r][c] = hv; Lo[r][c] = lv;
            }
        }
    __syncthreads();
    int r = tid >> 2, cq = (tid & 3) * 16;
    bs8 vh0, vh1, vl0, vl1;
#pragma unroll
    for (int e = 0; e < 8; e++) {
        vh0[e] = Hi[r][cq + e];     vh1[e] = Hi[r][cq + 8 + e];
        vl0[e] = Lo[r][cq + e];     vl1[e] = Lo[r][cq + 8 + e];
    }
    size_t ro = (size_t)(b * 128 + row0 + r) * 768 + col0 + cq;
    *(bs8*)(nodeh + ro) = vh0; *(bs8*)(nodeh + ro + 8) = vh1;
    *(bs8*)(nodel + ro) = vl0; *(bs8*)(nodel + ro + 8) = vl1;
}

// ---------------------------------------------------------------------------
// Fused graph-sum + batch-norm. grid 12, block 512.
// ---------------------------------------------------------------------------
__global__ __launch_bounds__(512) void gsum_bnorm_k(
    const float* __restrict__ node, const float* __restrict__ gamma,
    const float* __restrict__ beta, float* __restrict__ out)
{
    __shared__ float gbuf[8][64];
    __shared__ float mean_s[64], inv_s[64];
    int tid = threadIdx.x;
    int bg = tid >> 6, dl = tid & 63;
    int d = blockIdx.x * 64 + dl;
    float v = 0.f;
    for (int i = 0; i < 128; i++)
        v += node[(size_t)(bg * 128 + i) * 768 + d];
    gbuf[bg][dl] = v;
    __syncthreads();
    if (tid < 64) {
        float m = 0.f;
#pragma unroll
        for (int b = 0; b < 8; b++) m += gbuf[b][tid];
        m *= 0.125f;
        float var = 0.f;
#pragma unroll
        for (int b = 0; b < 8; b++) { float t = gbuf[b][tid] - m; var += t * t; }
        var *= 0.125f;
        mean_s[tid] = m;
        inv_s[tid] = 1.0f / sqrtf(var + EPS_V);
    }
    __syncthreads();
    out[bg * 768 + d] = gamma[d] * (v - mean_s[dl]) * inv_s[dl] + beta[d];
}

// ---------------------------------------------------------------------------
extern "C" void kernel_launch(void* const* d_in, const int* in_sizes, int n_in,
                              void* d_out, int out_size, void* d_ws, size_t ws_size,
                              hipStream_t stream)
{
    const float* feature = (const float*)d_in[0];
    // d_in[1] = aspect: unused by the reference
    const int*   adj     = (const int*)d_in[2];
    const float* W0      = (const float*)d_in[3];
    const float* b0      = (const float*)d_in[4];
    const float* W1      = (const float*)d_in[5];
    const float* b1      = (const float*)d_in[6];
    const float* A1      = (const float*)d_in[7];
    const float* ab1     = (const float*)d_in[8];
    const float* A2      = (const float*)d_in[9];
    const float* ab2     = (const float*)d_in[10];
    const float* gamma   = (const float*)d_in[11];
    const float* beta    = (const float*)d_in[12];

    float* ws    = (float*)d_ws;
    float* s     = ws;               // 2 x 131072 (split-K partials)
    float* p     = ws + 262144;      // 131072
    float* stats = ws + 393216;      // 16
    unsigned short* u = (unsigned short*)(ws + 393232);  // 16B-aligned
    unsigned short* Wt0h = u;                   // 589824 each
    unsigned short* Wt0l = Wt0h + 589824;
    unsigned short* Wt1h = Wt0l + 589824;
    unsigned short* Wt1l = Wt1h + 589824;
    unsigned short* A1th = Wt1l + 589824;       // 98304 each
    unsigned short* A1tl = A1th + 98304;
    unsigned short* fh   = A1tl + 98304;        // 786432 each from here
    unsigned short* fl   = fh + 786432;
    unsigned short* hh   = fl + 786432;
    unsigned short* hl   = hh + 786432;
    unsigned short* hth  = hl + 786432;
    unsigned short* htl  = hth + 786432;
    unsigned short* ndh  = htl + 786432;
    unsigned short* ndl  = ndh + 786432;
    unsigned short* ph   = ndl + 786432;        // 131072 each
    unsigned short* pl   = ph + 131072;

    float* out       = (float*)d_out;
    float* graph_out = out;          // (8,768)
    float* node_out  = out + 6144;   // (8,128,768); layer-0 scratch + final

    prep_k<<<504, 256, 0, stream>>>(W0, W1, A1, feature,
                                    Wt0h, Wt0l, Wt1h, Wt1l, A1th, A1tl, fh, fl);

    for (int layer = 0; layer < 2; layer++) {
        const unsigned short* Wth = layer ? Wt1h : Wt0h;
        const unsigned short* Wtl = layer ? Wt1l : Wt0l;
        const float* bb = layer ? b1 : b0;
        const unsigned short* Ahg = layer ? ndh : fh;
        const unsigned short* Alg = layer ? ndl : fl;
        gemm_mfma_bias_k<<<dim3(12, 16), 256, 0, stream>>>(Ahg, Alg, Wth, Wtl, bb,
                                                           hh, hl, hth, htl);
        sproj_mfma_k<<<dim3(2, 16, 2), 256, 0, stream>>>(hh, hl, A1th, A1tl, s);
        score_k<<<dim3(8, 8), 256, 0, stream>>>(s, adj, ab1, A2, ab2, p);
        softmax_k<<<8, 1024, 0, stream>>>(p, ph, pl, stats);
        attn_mfma_k<<<dim3(12, 2, 8), 256, 0, stream>>>(ph, pl, hth, htl, stats,
                                                        node_out, ndh, ndl);
    }
    gsum_bnorm_k<<<12, 512, 0, stream>>>(node_out, gamma, beta, graph_out);
}